// Round 2
// baseline (121.473 us; speedup 1.0000x reference)
//
#include <hip/hip_runtime.h>
#include <cstdint>
#include <cstddef>

// HyperNetwork: k[b,c,f] = sum_n x[b,c,n] * W_eff[c,f,n] + b_eff[c,f]
//   W_eff[c,f,n] = sum_z W_out[f,z] * W_in[c,z,n]
//   b_eff[c,f]   = sum_z b_in[c,z]  * W_out[f,z] + b_out[f]
// Output [B,1,C,3,3] flat == [B,C,9] since OUT_CH==1.
//
// Structure: one block per channel c. Phase 1 builds W_eff[c] (9x256) in LDS
// (W_in read exactly once, coalesced). Phase 2: lane-per-row streaming — each
// of the 256 threads owns one b-row, streams its 1KB z-row from global as
// float4, multiplies against broadcast ds_read_b128 of W_eff. NO barriers in
// the main loop, no x staging -> no vmcnt(0) drains, compiler free to pipeline.

#define BB 256
#define CC 512
#define NZ 256
#define ZD 64
#define NF 9

typedef __attribute__((ext_vector_type(4))) float f32x4;

__global__ __launch_bounds__(256, 2)
void hyper_v2(const float* __restrict__ z,
              const float* __restrict__ W_in,
              const float* __restrict__ b_in,
              const float* __restrict__ W_out,
              const float* __restrict__ b_out,
              float* __restrict__ out)
{
  __shared__ __align__(16) float w_lds[NF * NZ];   // 9216 B  W_eff[f][n]
  __shared__ float b_lds[12];                      // b_eff

  const int c = blockIdx.x;
  const int t = threadIdx.x;

  // ---------- Phase 1: W_eff[f][n] for n = t ----------
  {
    float acc[NF];
    #pragma unroll
    for (int f = 0; f < NF; ++f) acc[f] = 0.f;
    const float* wi = W_in + (size_t)c * ZD * NZ + t;
    #pragma unroll 4
    for (int zz = 0; zz < ZD; ++zz) {
      float v = wi[(size_t)zz * NZ];          // 256 threads -> 1KB coalesced
      #pragma unroll
      for (int f = 0; f < NF; ++f)
        acc[f] += W_out[f * ZD + zz] * v;     // W_out uniform -> scalar loads
    }
    #pragma unroll
    for (int f = 0; f < NF; ++f)
      w_lds[f * NZ + t] = acc[f];
  }
  if (t < NF) {
    float bacc = b_out[t];
    for (int zz = 0; zz < ZD; ++zz)
      bacc += b_in[(size_t)c * ZD + zz] * W_out[t * ZD + zz];
    b_lds[t] = bacc;
  }

  __syncthreads();   // the ONLY barrier

  // ---------- Phase 2: lane-per-row streaming ----------
  // thread t owns batch row b = t; z row is 1KB contiguous.
  const float* xrow = z + ((size_t)t * CC + c) * NZ;
  float acc[NF];
  #pragma unroll
  for (int f = 0; f < NF; ++f) acc[f] = 0.f;

  #pragma unroll 4
  for (int k = 0; k < NZ / 4; ++k) {
    f32x4 xv = *(const f32x4*)(xrow + 4 * k);
    #pragma unroll
    for (int f = 0; f < NF; ++f) {
      f32x4 wf = *(const f32x4*)&w_lds[f * NZ + 4 * k];  // wave-uniform bcast
      acc[f] += xv.x * wf.x;
      acc[f] += xv.y * wf.y;
      acc[f] += xv.z * wf.z;
      acc[f] += xv.w * wf.w;
    }
  }

  float* orow = out + ((size_t)t * CC + c) * NF;
  #pragma unroll
  for (int f = 0; f < NF; ++f)
    orow[f] = acc[f] + b_lds[f];
}

extern "C" void kernel_launch(void* const* d_in, const int* in_sizes, int n_in,
                              void* d_out, int out_size, void* d_ws, size_t ws_size,
                              hipStream_t stream) {
  const float* z     = (const float*)d_in[0];
  const float* W_in  = (const float*)d_in[1];
  const float* b_in  = (const float*)d_in[2];
  const float* W_out = (const float*)d_in[3];
  const float* b_out = (const float*)d_in[4];
  float* out = (float*)d_out;

  hipLaunchKernelGGL(hyper_v2, dim3(CC), dim3(256), 0, stream,
                     z, W_in, b_in, W_out, b_out, out);
}

// Round 3
// 49.437 us; speedup vs baseline: 2.4571x; 2.4571x over previous
//
#include <hip/hip_runtime.h>
#include <cstdint>
#include <cstddef>

// HyperNetwork: k[b,c,f] = sum_n x[b,c,n] * W_eff[c,f,n] + b_eff[c,f]
//   W_eff[c] = W_out(9x64) @ W_in[c](64x256)  -> built once into d_ws (kernel A)
//   Kernel B: 2048 blocks = (bchunk 0..3, c 0..511), wave-cooperative rows:
//   8 lanes per row (each lane a contiguous 128B slice of the 1KB row),
//   W_eff broadcast from LDS (XOR-swizzled, conflict-free), shfl_xor reduce.
//   Zero barriers in the main loop.

#define CC 512
#define NZ 256
#define ZD 64
#define NF 9
#define BB 256

typedef __attribute__((ext_vector_type(4))) float f32x4;

// ---------------- Kernel A: build W_eff + b_eff into ws ----------------
__global__ __launch_bounds__(256, 2)
void weff_build(const float* __restrict__ W_in, const float* __restrict__ b_in,
                const float* __restrict__ W_out, const float* __restrict__ b_out,
                float* __restrict__ ws_w, float* __restrict__ ws_b)
{
  const int c = blockIdx.x;
  const int t = threadIdx.x;   // n
  float acc[NF];
#pragma unroll
  for (int f = 0; f < NF; ++f) acc[f] = 0.f;
  const float* wi = W_in + (size_t)c * ZD * NZ + t;
#pragma unroll 4
  for (int zz = 0; zz < ZD; ++zz) {
    float v = wi[(size_t)zz * NZ];          // 1KB coalesced per iter
#pragma unroll
    for (int f = 0; f < NF; ++f) acc[f] += W_out[f * ZD + zz] * v;  // scalar
  }
#pragma unroll
  for (int f = 0; f < NF; ++f)
    ws_w[(size_t)c * (NF * NZ) + f * NZ + t] = acc[f];
  if (t < NF) {
    float bacc = b_out[t];
    for (int zz = 0; zz < ZD; ++zz)
      bacc += b_in[(size_t)c * ZD + zz] * W_out[t * ZD + zz];
    ws_b[c * 16 + t] = bacc;
  }
}

// ---------------- Kernel B: apply ----------------
__global__ __launch_bounds__(256, 4)
void hyper_apply(const float* __restrict__ z,
                 const float* __restrict__ ws_w,
                 const float* __restrict__ ws_b,
                 float* __restrict__ out)
{
  __shared__ __align__(16) f32x4 w_lds[NF * 64];  // swizzled f32x4 slots
  __shared__ float b_lds[16];

  const int blk = blockIdx.x;
  const int c = blk & (CC - 1);     // same-c blocks are 512 apart -> same XCD
  const int bchunk = blk >> 9;      // 0..3
  const int t = threadIdx.x;

  // cooperative load of W_eff[c] with XOR slot swizzle: orig slot s -> s^((s>>3)&7)
  {
    const f32x4* src = (const f32x4*)(ws_w + (size_t)c * (NF * NZ));
#pragma unroll
    for (int i = t; i < NF * 64; i += 256) {
      const int f = i >> 6, s = i & 63;
      w_lds[f * 64 + (s ^ ((s >> 3) & 7))] = src[i];
    }
    if (t < 16) b_lds[t] = ws_b[c * 16 + t];
  }
  __syncthreads();   // the only barrier

  const int lane = t & 63;
  const int w = t >> 6;
  const int g = lane & 7;        // n-chunk id: floats [g*32, g*32+32)
  const int rg = lane >> 3;      // row-in-pass 0..7

#pragma unroll
  for (int p = 0; p < 2; ++p) {
    const int r = w * 16 + p * 8 + rg;         // 0..63 within block
    const int b = bchunk * 64 + r;
    const float* xr = z + ((size_t)b * CC + c) * NZ + g * 32;
    f32x4 xv[8];
#pragma unroll
    for (int j = 0; j < 8; ++j) xv[j] = *(const f32x4*)(xr + j * 4);

    float acc[NF];
#pragma unroll
    for (int f = 0; f < NF; ++f) acc[f] = 0.f;
#pragma unroll
    for (int j = 0; j < 8; ++j) {
      const int slot = (g * 8 + j) ^ g;        // swizzled read: banks j^g -> conflict-free
#pragma unroll
      for (int f = 0; f < NF; ++f) {
        f32x4 wf = w_lds[f * 64 + slot];
        acc[f] += xv[j].x * wf.x;
        acc[f] += xv[j].y * wf.y;
        acc[f] += xv[j].z * wf.z;
        acc[f] += xv[j].w * wf.w;
      }
    }

    // reduce over the 8 lanes sharing a row (g axis)
#pragma unroll
    for (int m = 1; m < 8; m <<= 1)
#pragma unroll
      for (int f = 0; f < NF; ++f)
        acc[f] += __shfl_xor(acc[f], m, 64);

    // lane g writes f=g (static-index select chain, no scratch)
    float o = acc[0];
#pragma unroll
    for (int f = 1; f < 8; ++f) o = (g == f) ? acc[f] : o;
    const size_t ob = ((size_t)b * CC + c) * NF;
    out[ob + g] = o + b_lds[g];
    if (g == 0) out[ob + 8] = acc[8] + b_lds[8];
  }
}

// ---------------- Fallback (R1 kernel) if ws too small ----------------
#define XROW 260
__device__ __forceinline__ void gload_lds16(const float* g, float* l) {
  __builtin_amdgcn_global_load_lds(
      (const __attribute__((address_space(1))) void*)g,
      (__attribute__((address_space(3))) void*)l, 16, 0, 0);
}

__global__ __launch_bounds__(256, 2)
void hyper_fused(const float* __restrict__ z, const float* __restrict__ W_in,
                 const float* __restrict__ b_in, const float* __restrict__ W_out,
                 const float* __restrict__ b_out, float* __restrict__ out)
{
  __shared__ __align__(16) float w_lds[NF * NZ];
  __shared__ float b_lds[16];
  __shared__ __align__(16) float x_lds[64 * XROW];
  float* part = x_lds;
  const int c = blockIdx.x, t = threadIdx.x, lane = t & 63, w = t >> 6;
  {
    float acc[NF];
#pragma unroll
    for (int f = 0; f < NF; ++f) acc[f] = 0.f;
    const float* wi = W_in + (size_t)c * ZD * NZ + t;
    for (int zz = 0; zz < ZD; ++zz) {
      float v = wi[(size_t)zz * NZ];
#pragma unroll
      for (int f = 0; f < NF; ++f) acc[f] += W_out[f * ZD + zz] * v;
    }
#pragma unroll
    for (int f = 0; f < NF; ++f) w_lds[f * NZ + t] = acc[f];
  }
  if (t < NF) {
    float bacc = b_out[t];
    for (int zz = 0; zz < ZD; ++zz)
      bacc += b_in[(size_t)c * ZD + zz] * W_out[t * ZD + zz];
    b_lds[t] = bacc;
  }
  __syncthreads();
  for (int bc = 0; bc < 4; ++bc) {
    const int r0 = w * 16;
#pragma unroll
    for (int j = 0; j < 16; ++j) {
      const int r = r0 + j, b = bc * 64 + r;
      gload_lds16(z + ((size_t)b * CC + c) * NZ + lane * 4, &x_lds[r * XROW]);
    }
    __syncthreads();
    float acc[NF];
#pragma unroll
    for (int f = 0; f < NF; ++f) acc[f] = 0.f;
    const int n0 = w * 64;
#pragma unroll
    for (int g4 = 0; g4 < 16; ++g4) {
      f32x4 xv = *(const f32x4*)&x_lds[lane * XROW + n0 + g4 * 4];
#pragma unroll
      for (int f = 0; f < NF; ++f) {
        f32x4 wf = *(const f32x4*)&w_lds[f * NZ + n0 + g4 * 4];
        acc[f] += xv.x * wf.x; acc[f] += xv.y * wf.y;
        acc[f] += xv.z * wf.z; acc[f] += xv.w * wf.w;
      }
    }
    __syncthreads();
#pragma unroll
    for (int f = 0; f < NF; ++f) part[(w * 64 + lane) * NF + f] = acc[f];
    __syncthreads();
    const int b = bc * 64 + lane;
    for (int f = w; f < NF; f += 4) {
      float s = part[(0 * 64 + lane) * NF + f] + part[(1 * 64 + lane) * NF + f]
              + part[(2 * 64 + lane) * NF + f] + part[(3 * 64 + lane) * NF + f];
      out[((size_t)b * CC + c) * NF + f] = s + b_lds[f];
    }
    __syncthreads();
  }
}

extern "C" void kernel_launch(void* const* d_in, const int* in_sizes, int n_in,
                              void* d_out, int out_size, void* d_ws, size_t ws_size,
                              hipStream_t stream) {
  const float* z     = (const float*)d_in[0];
  const float* W_in  = (const float*)d_in[1];
  const float* b_in  = (const float*)d_in[2];
  const float* W_out = (const float*)d_in[3];
  const float* b_out = (const float*)d_in[4];
  float* out = (float*)d_out;

  const size_t ws_need = ((size_t)CC * NF * NZ + (size_t)CC * 16) * sizeof(float);
  if (ws_size >= ws_need) {
    float* ws_w = (float*)d_ws;
    float* ws_b = ws_w + (size_t)CC * NF * NZ;
    hipLaunchKernelGGL(weff_build, dim3(CC), dim3(256), 0, stream,
                       W_in, b_in, W_out, b_out, ws_w, ws_b);
    hipLaunchKernelGGL(hyper_apply, dim3(4 * CC), dim3(256), 0, stream,
                       z, ws_w, ws_b, out);
  } else {
    hipLaunchKernelGGL(hyper_fused, dim3(CC), dim3(256), 0, stream,
                       z, W_in, b_in, W_out, b_out, out);
  }
}

// Round 4
// 44.615 us; speedup vs baseline: 2.7227x; 1.1081x over previous
//
#include <hip/hip_runtime.h>
#include <cstdint>
#include <cstddef>

// HyperNetwork via MFMA:
//   Out[b,c,f] = sum_n X[b,c,n] * W_eff[c,f,n] + b_eff[c,f]
//   Kernel A: W_eff[c] = W_out(9x64) @ W_in[c](64x256), emitted as bf16 hi/lo
//             MFMA fragments (A-operand layout) into d_ws + b_eff.
//   Kernel B: per channel, D(16f x 16b tiles) = W(A-op) * X^T(B-op) using
//             mfma_f32_16x16x32_bf16, 3-term hi/lo for ~fp32 precision.

#define CC 512
#define NZ 256
#define ZD 64
#define NF 9
#define BB 256

typedef __attribute__((ext_vector_type(4))) float f32x4;
typedef __attribute__((ext_vector_type(8))) short bf16x8;
typedef __attribute__((ext_vector_type(4))) short short4v;

__device__ __forceinline__ unsigned short f2bf(float f) {
  unsigned int u = __builtin_bit_cast(unsigned int, f);
  unsigned int r = (u + 0x7fffu + ((u >> 16) & 1u)) >> 16;   // RTNE
  return (unsigned short)r;
}
__device__ __forceinline__ float bf2f(unsigned short u) {
  unsigned int x = ((unsigned int)u) << 16;
  return __builtin_bit_cast(float, x);
}

// ---------------- Kernel A: W_eff -> bf16 hi/lo fragments + bias ----------
__global__ __launch_bounds__(256, 2)
void weff_build(const float* __restrict__ W_in, const float* __restrict__ b_in,
                const float* __restrict__ W_out, const float* __restrict__ b_out,
                unsigned short* __restrict__ ws_wh,
                unsigned short* __restrict__ ws_wl,
                float* __restrict__ ws_b)
{
  __shared__ float w_lds[NF * NZ];
  const int c = blockIdx.x, t = threadIdx.x;
  {
    float acc[NF];
#pragma unroll
    for (int f = 0; f < NF; ++f) acc[f] = 0.f;
    const float* wi = W_in + (size_t)c * ZD * NZ + t;
#pragma unroll 4
    for (int zz = 0; zz < ZD; ++zz) {
      float v = wi[(size_t)zz * NZ];              // 1KB coalesced per iter
#pragma unroll
      for (int f = 0; f < NF; ++f) acc[f] += W_out[f * ZD + zz] * v;  // s_load
    }
#pragma unroll
    for (int f = 0; f < NF; ++f) w_lds[f * NZ + t] = acc[f];
  }
  if (t < 16) {
    float bacc = 0.f;
    if (t < NF) {
      bacc = b_out[t];
      for (int zz = 0; zz < ZD; ++zz)
        bacc += b_in[(size_t)c * ZD + zz] * W_out[t * ZD + zz];
    }
    ws_b[c * 16 + t] = bacc;                      // f>=9 zeroed
  }
  __syncthreads();

  // Emit fragments: lane l holds W[f=l&15][n = ks*32 + (l>>4)*8 + j], j=0..7
#pragma unroll
  for (int p = 0; p < 2; ++p) {
    const int u = p * 256 + t;
    const int ks = u >> 6, l = u & 63;
    const int f = l & 15, g = l >> 4;
    bf16x8 hv, lv;
#pragma unroll
    for (int j = 0; j < 8; ++j) {
      float v = (f < NF) ? w_lds[f * NZ + ks * 32 + g * 8 + j] : 0.f;
      unsigned short hh = f2bf(v);
      hv[j] = (short)hh;
      lv[j] = (short)f2bf(v - bf2f(hh));
    }
    const size_t off = ((size_t)(c * 8 + ks) * 64 + l) * 8;
    *(bf16x8*)(ws_wh + off) = hv;                 // coalesced 16B/lane
    *(bf16x8*)(ws_wl + off) = lv;
  }
}

// ---------------- Kernel B: MFMA apply ----------------
__global__ __launch_bounds__(256, 2)
void hyper_mfma(const float* __restrict__ z,
                const unsigned short* __restrict__ ws_wh,
                const unsigned short* __restrict__ ws_wl,
                const float* __restrict__ ws_b,
                float* __restrict__ out)
{
  __shared__ unsigned short x_h[64 * 256];   // 32 KB, XOR-swizzled 16B slots
  __shared__ unsigned short x_l[64 * 256];   // 32 KB

  const int c = blockIdx.x;
  const int t = threadIdx.x;
  const int lane = t & 63;
  const int w = t >> 6;
  const int g = lane >> 4;

  // Preload all W fragments (8 k-steps, hi+lo) -> 64 VGPRs
  bf16x8 wh[8], wl[8];
#pragma unroll
  for (int ks = 0; ks < 8; ++ks) {
    const size_t off = ((size_t)(c * 8 + ks) * 64 + lane) * 8;
    wh[ks] = *(const bf16x8*)(ws_wh + off);
    wl[ks] = *(const bf16x8*)(ws_wl + off);
  }
  const f32x4 bv = *(const f32x4*)(ws_b + c * 16 + g * 4);

  const int s4 = t & 63;        // f32x4 granule within a row (0..63)
  const int r_base = t >> 6;    // rows r_base + 4k, k=0..15

  f32x4 xv[16];
  // prefetch chunk 0 (each wave instr reads one contiguous 1KB row)
#pragma unroll
  for (int k = 0; k < 16; ++k) {
    const int b = r_base + 4 * k;
    xv[k] = *(const f32x4*)(z + ((size_t)b * CC + c) * NZ + s4 * 4);
  }

  for (int bc = 0; bc < 4; ++bc) {
    // cvt + swizzled LDS write (all lanes of a wave write within one row: free)
#pragma unroll
    for (int k = 0; k < 16; ++k) {
      const int r = r_base + 4 * k;
      const int sl = (((s4 >> 1) ^ (r & 7)) << 3) + ((s4 & 1) << 2);
      short4v hv, lv;
#pragma unroll
      for (int j = 0; j < 4; ++j) {
        float v = xv[k][j];
        unsigned short hh = f2bf(v);
        hv[j] = (short)hh;
        lv[j] = (short)f2bf(v - bf2f(hh));
      }
      *(short4v*)&x_h[r * 256 + sl] = hv;
      *(short4v*)&x_l[r * 256 + sl] = lv;
    }
    __syncthreads();

    // prefetch next chunk's globals (overlaps the MFMA phase)
    if (bc < 3) {
#pragma unroll
      for (int k = 0; k < 16; ++k) {
        const int b = (bc + 1) * 64 + r_base + 4 * k;
        xv[k] = *(const f32x4*)(z + ((size_t)b * CC + c) * NZ + s4 * 4);
      }
    }

    // compute: wave w -> b-columns [w*16, w*16+16); D = W(A) * X^T(B)
    const int xrow = w * 16 + (lane & 15);
    f32x4 acc = {0.f, 0.f, 0.f, 0.f};
#pragma unroll
    for (int ks = 0; ks < 8; ++ks) {
      const int sl = (((4 * ks + g) ^ (xrow & 7)) << 3);
      bf16x8 xh = *(const bf16x8*)&x_h[xrow * 256 + sl];
      bf16x8 xl = *(const bf16x8*)&x_l[xrow * 256 + sl];
      acc = __builtin_amdgcn_mfma_f32_16x16x32_bf16(wh[ks], xh, acc, 0, 0, 0);
      acc = __builtin_amdgcn_mfma_f32_16x16x32_bf16(wl[ks], xh, acc, 0, 0, 0);
      acc = __builtin_amdgcn_mfma_f32_16x16x32_bf16(wh[ks], xl, acc, 0, 0, 0);
    }

    // epilogue: D row = f = g*4+reg (verified C/D map), col = b = lane&15
    {
      const int bcol = bc * 64 + w * 16 + (lane & 15);
      float* ob = out + ((size_t)bcol * CC + c) * NF;
      if (g < 2) {
#pragma unroll
        for (int reg = 0; reg < 4; ++reg)
          ob[g * 4 + reg] = acc[reg] + bv[reg];
      } else if (g == 2) {
        ob[8] = acc[0] + bv[0];
      }
    }
    __syncthreads();   // LDS reads done before next chunk's writes
  }
}

// ---------------- Fallback (R1 kernel, 44.9us) if ws too small ----------
#define XROW 260
__device__ __forceinline__ void gload_lds16(const float* g, float* l) {
  __builtin_amdgcn_global_load_lds(
      (const __attribute__((address_space(1))) void*)g,
      (__attribute__((address_space(3))) void*)l, 16, 0, 0);
}

__global__ __launch_bounds__(256, 2)
void hyper_fused(const float* __restrict__ z, const float* __restrict__ W_in,
                 const float* __restrict__ b_in, const float* __restrict__ W_out,
                 const float* __restrict__ b_out, float* __restrict__ out)
{
  __shared__ __align__(16) float w_lds[NF * NZ];
  __shared__ float b_lds[16];
  __shared__ __align__(16) float x_lds[64 * XROW];
  float* part = x_lds;
  const int c = blockIdx.x, t = threadIdx.x, lane = t & 63, w = t >> 6;
  {
    float acc[NF];
#pragma unroll
    for (int f = 0; f < NF; ++f) acc[f] = 0.f;
    const float* wi = W_in + (size_t)c * ZD * NZ + t;
    for (int zz = 0; zz < ZD; ++zz) {
      float v = wi[(size_t)zz * NZ];
#pragma unroll
      for (int f = 0; f < NF; ++f) acc[f] += W_out[f * ZD + zz] * v;
    }
#pragma unroll
    for (int f = 0; f < NF; ++f) w_lds[f * NZ + t] = acc[f];
  }
  if (t < NF) {
    float bacc = b_out[t];
    for (int zz = 0; zz < ZD; ++zz)
      bacc += b_in[(size_t)c * ZD + zz] * W_out[t * ZD + zz];
    b_lds[t] = bacc;
  }
  __syncthreads();
  for (int bc = 0; bc < 4; ++bc) {
    const int r0 = w * 16;
#pragma unroll
    for (int j = 0; j < 16; ++j) {
      const int r = r0 + j, b = bc * 64 + r;
      gload_lds16(z + ((size_t)b * CC + c) * NZ + lane * 4, &x_lds[r * XROW]);
    }
    __syncthreads();
    float acc[NF];
#pragma unroll
    for (int f = 0; f < NF; ++f) acc[f] = 0.f;
    const int n0 = w * 64;
#pragma unroll
    for (int g4 = 0; g4 < 16; ++g4) {
      f32x4 xvv = *(const f32x4*)&x_lds[lane * XROW + n0 + g4 * 4];
#pragma unroll
      for (int f = 0; f < NF; ++f) {
        f32x4 wf = *(const f32x4*)&w_lds[f * NZ + n0 + g4 * 4];
        acc[f] += xvv.x * wf.x; acc[f] += xvv.y * wf.y;
        acc[f] += xvv.z * wf.z; acc[f] += xvv.w * wf.w;
      }
    }
    __syncthreads();
#pragma unroll
    for (int f = 0; f < NF; ++f) part[(w * 64 + lane) * NF + f] = acc[f];
    __syncthreads();
    const int b = bc * 64 + lane;
    for (int f = w; f < NF; f += 4) {
      float s = part[(0 * 64 + lane) * NF + f] + part[(1 * 64 + lane) * NF + f]
              + part[(2 * 64 + lane) * NF + f] + part[(3 * 64 + lane) * NF + f];
      out[((size_t)b * CC + c) * NF + f] = s + b_lds[f];
    }
    __syncthreads();
  }
}

extern "C" void kernel_launch(void* const* d_in, const int* in_sizes, int n_in,
                              void* d_out, int out_size, void* d_ws, size_t ws_size,
                              hipStream_t stream) {
  const float* z     = (const float*)d_in[0];
  const float* W_in  = (const float*)d_in[1];
  const float* b_in  = (const float*)d_in[2];
  const float* W_out = (const float*)d_in[3];
  const float* b_out = (const float*)d_in[4];
  float* out = (float*)d_out;

  const size_t frag_elems = (size_t)CC * 8 * 64 * 8;           // ushorts (4 MB)
  const size_t ws_need = frag_elems * 2 * sizeof(unsigned short)
                       + (size_t)CC * 16 * sizeof(float);
  if (ws_size >= ws_need) {
    unsigned short* ws_wh = (unsigned short*)d_ws;
    unsigned short* ws_wl = ws_wh + frag_elems;
    float* ws_b = (float*)(ws_wl + frag_elems);
    hipLaunchKernelGGL(weff_build, dim3(CC), dim3(256), 0, stream,
                       W_in, b_in, W_out, b_out, ws_wh, ws_wl, ws_b);
    hipLaunchKernelGGL(hyper_mfma, dim3(CC), dim3(256), 0, stream,
                       z, ws_wh, ws_wl, ws_b, out);
  } else {
    hipLaunchKernelGGL(hyper_fused, dim3(CC), dim3(256), 0, stream,
                       z, W_in, b_in, W_out, b_out, out);
  }
}